// Round 6
// baseline (70.321 us; speedup 1.0000x reference)
//
#include <hip/hip_runtime.h>
#include <math.h>

typedef float v2f __attribute__((ext_vector_type(2)));

#define N_PTS 4096
#define BLOCK 512                 // 8 waves
#define RPB 4                     // rows per block
#define CHUNK 2048                // points staged per pass (32 KB LDS)
#define SLICES (BLOCK / RPB)      // 128 j-slices
#define JPS (CHUNK / SLICES)      // 16 j's per slice per pass
#define PPT (CHUNK / BLOCK)       // 4 staged points per thread per pass

// Fused: chunked LDS staging of scaled (pos*s, vel), per-(row,slice) fixed-shift
// softmax accumulation, in-block group_vel, analytic diagonal removal.
__global__ __launch_bounds__(BLOCK, 6) void fused_kernel(
        const float* __restrict__ states,
        const float* __restrict__ log_tau_p,
        float* __restrict__ out) {
    __shared__ float4 pvs[CHUNK];       // 32 KB: (pos.x*s, pos.y*s, vel.x, vel.y)
    __shared__ float wsum[8][2];        // per-wave vel sums
    __shared__ float red[8][RPB][10];   // cross-wave partial states

    const int tid  = threadIdx.x;
    const int lane = tid & 63;
    const int wave = tid >> 6;

    // s = (1/tau) * log2(e); w = exp(-dist/tau) = exp2(-s*dist)
    const float s    = __expf(-log_tau_p[0]) * 1.4426950408889634f;
    const float eps2 = 1e-8f * s * s;

    // ---- this lane's row (pos scaled by s, vel unscaled) ----
    const int rowg = blockIdx.x * RPB + (lane & 3);
    const float4 r0 = *reinterpret_cast<const float4*>(states + rowg * 8);
    const float4 r1 = *reinterpret_cast<const float4*>(states + rowg * 8 + 4);
    const v2f pis = { (r0.x + r0.z) * 0.5f * s, (r0.y + r0.w) * 0.5f * s };
    const v2f piv = { (r1.x + r1.z) * 0.5f,     (r1.y + r1.w) * 0.5f };

    const int slice = wave * (SLICES / 8) + (lane >> 2);

    float l = 0.f, svx = 0.f, svy = 0.f;
    v2f S1p = {0.f, 0.f}, S1v = {0.f, 0.f}, S2p = {0.f, 0.f}, S2v = {0.f, 0.f};

    #pragma unroll
    for (int pass = 0; pass < N_PTS / CHUNK; ++pass) {
        // ---- stage CHUNK points (identical arithmetic to pis/piv above) ----
        const int J0 = pass * CHUNK;
        #pragma unroll
        for (int k = 0; k < PPT; ++k) {
            const int p = tid + k * BLOCK;
            const float4 s0 = *reinterpret_cast<const float4*>(states + (J0 + p) * 8);
            const float4 s1 = *reinterpret_cast<const float4*>(states + (J0 + p) * 8 + 4);
            float4 e;
            e.x = (s0.x + s0.z) * 0.5f * s;
            e.y = (s0.y + s0.w) * 0.5f * s;
            e.z = (s1.x + s1.z) * 0.5f;
            e.w = (s1.y + s1.w) * 0.5f;
            pvs[p] = e;
            svx += e.z; svy += e.w;
        }
        __syncthreads();   // chunk staged

        // ---- accumulate this chunk ----
        #pragma unroll 8
        for (int tt = 0; tt < JPS; ++tt) {
            const float4 q = pvs[slice + tt * SLICES];
            v2f dp = { pis.x - q.x, pis.y - q.y };
            v2f dv = { piv.x - q.z, piv.y - q.w };
            float d2 = fmaf(dp.x, dp.x, fmaf(dp.y, dp.y, eps2));
            float w  = __builtin_amdgcn_exp2f(-__builtin_amdgcn_sqrtf(d2));
            l += w;
            v2f wv = { w, w };
            v2f t0 = dp * wv;
            v2f t1 = dv * wv;
            S1p += t0;
            S1v += t1;
            S2p += t0 * dp;
            S2v += t1 * dv;
        }
        __syncthreads();   // done with chunk before restage
    }

    // ---- per-wave vel sums (each block staged all N points once) ----
    float tx = svx, ty = svy;
    #pragma unroll
    for (int off = 32; off; off >>= 1) {
        tx += __shfl_down(tx, off);
        ty += __shfl_down(ty, off);
    }
    if (lane == 0) { wsum[wave][0] = tx; wsum[wave][1] = ty; }

    // ---- in-wave merge over 16 slices (lanes stride 4): pure adds ----
    #pragma unroll
    for (int off = 4; off < 64; off <<= 1) {
        l     += __shfl_xor(l, off);
        S1p.x += __shfl_xor(S1p.x, off);
        S1p.y += __shfl_xor(S1p.y, off);
        S1v.x += __shfl_xor(S1v.x, off);
        S1v.y += __shfl_xor(S1v.y, off);
        S2p.x += __shfl_xor(S2p.x, off);
        S2p.y += __shfl_xor(S2p.y, off);
        S2v.x += __shfl_xor(S2v.x, off);
        S2v.y += __shfl_xor(S2v.y, off);
    }
    if (lane < RPB) {
        float* rr = red[wave][lane];
        rr[0] = l;
        rr[1] = S1p.x; rr[2] = S1p.y; rr[3] = S1v.x; rr[4] = S1v.y;
        rr[5] = S2p.x; rr[6] = S2p.y; rr[7] = S2v.x; rr[8] = S2v.y;
    }
    __syncthreads();

    // ---- finalize: 4 threads, one row each ----
    if (tid < RPB) {
        float acc[9];
        #pragma unroll
        for (int cc = 0; cc < 9; ++cc) acc[cc] = red[0][tid][cc];
        #pragma unroll
        for (int wv = 1; wv < 8; ++wv)
            #pragma unroll
            for (int cc = 0; cc < 9; ++cc) acc[cc] += red[wv][tid][cc];

        // diagonal weight (bit-identical float path as in-loop with dp=dv=0)
        const float w_diag = __builtin_amdgcn_exp2f(-__builtin_amdgcn_sqrtf(eps2));
        const float inv_l = 1.0f / (acc[0] - w_diag);
        const float inv_s = 1.0f / s;

        float gvx = 0.f, gvy = 0.f;
        #pragma unroll
        for (int wv = 0; wv < 8; ++wv) { gvx += wsum[wv][0]; gvy += wsum[wv][1]; }
        gvx *= (1.0f / N_PTS);
        gvy *= (1.0f / N_PTS);

        const int row = blockIdx.x * RPB + tid;
        const float4 q1 = *reinterpret_cast<const float4*>(states + row * 8 + 4);
        const float rvx = (q1.x + q1.z) * 0.5f;
        const float rvy = (q1.y + q1.w) * 0.5f;

        // unscale: S1p holds s*sum(w*dp), S2p holds s^2*sum(w*dp^2)
        float mu[4], sg[4];
        mu[0] = acc[1] * inv_l * inv_s;
        mu[1] = acc[2] * inv_l * inv_s;
        mu[2] = acc[3] * inv_l;
        mu[3] = acc[4] * inv_l;
        const float inv_s2 = inv_s * inv_s;
        float e2[4];
        e2[0] = acc[5] * inv_l * inv_s2;
        e2[1] = acc[6] * inv_l * inv_s2;
        e2[2] = acc[7] * inv_l;
        e2[3] = acc[8] * inv_l;
        #pragma unroll
        for (int d = 0; d < 4; ++d)
            sg[d] = __builtin_amdgcn_sqrtf(fmaf(-mu[d], mu[d], e2[d]) + 1e-6f);

        float4* o = reinterpret_cast<float4*>(out + row * 12);
        o[0] = make_float4(mu[0], mu[1], mu[2], mu[3]);
        o[1] = make_float4(sg[0], sg[1], sg[2], sg[3]);
        o[2] = make_float4(gvx, gvy, rvx - gvx, rvy - gvy);
    }
}

extern "C" void kernel_launch(void* const* d_in, const int* in_sizes, int n_in,
                              void* d_out, int out_size, void* d_ws, size_t ws_size,
                              hipStream_t stream) {
    const float* states  = (const float*)d_in[0];
    const float* log_tau = (const float*)d_in[1];
    float* out = (float*)d_out;
    fused_kernel<<<N_PTS / RPB, BLOCK, 0, stream>>>(states, log_tau, out);
}